// Round 11
// baseline (301.811 us; speedup 1.0000x reference)
//
#include <hip/hip_runtime.h>
#include <stdint.h>
#include <stddef.h>

#define Bsz 2
#define Ssz 4096
#define Csz 640
#define Hn 10
#define Dh 64
#define NSPLIT 4
#define QROWS 81920   // B*H*S = 20*4096

typedef __attribute__((ext_vector_type(8))) short bf16x8;
typedef __attribute__((ext_vector_type(4))) float f32x4;
typedef __attribute__((ext_vector_type(16))) float f32x16;

typedef __attribute__((address_space(1))) void as1_void;
typedef __attribute__((address_space(3))) void as3_void;

__device__ __forceinline__ void async16(const void* g, void* l) {
  __builtin_amdgcn_global_load_lds((as1_void*)(g), (as3_void*)(l), 16, 0, 0);
}

__device__ __forceinline__ ushort f2bf(float f) {
  union { float f; uint32_t u; } v; v.f = f;
  return (ushort)((v.u + 0x7FFFu + ((v.u >> 16) & 1u)) >> 16);
}

// pack two fp32 -> bf16x2 (truncation) in one v_perm_b32
__device__ __forceinline__ uint32_t pack_bf16(float lo, float hi) {
  return __builtin_amdgcn_perm(__float_as_uint(hi), __float_as_uint(lo), 0x07060302u);
}

__device__ __forceinline__ float bf_lo(uint32_t u) {
  return __uint_as_float(u << 16);
}
__device__ __forceinline__ float bf_hi(uint32_t u) {
  return __uint_as_float(u & 0xFFFF0000u);
}

// one-instruction exp2
__device__ __forceinline__ float fast_exp2(float x) {
#if __has_builtin(__builtin_amdgcn_exp2f)
  return __builtin_amdgcn_exp2f(x);
#else
  return __exp2f(x);
#endif
}

// scale folded into Q: 1/sqrt(64) * log2(e)
#define QSCALE 0.1803368801111204f

__global__ __launch_bounds__(256) void cvt_bf16(const float* __restrict__ in,
                                                ushort* __restrict__ out, int n4) {
  int i = blockIdx.x * 256 + threadIdx.x;
  if (i < n4) {
    const float4 v = ((const float4*)in)[i];
    ushort4 o;
    o.x = f2bf(v.x); o.y = f2bf(v.y); o.z = f2bf(v.z); o.w = f2bf(v.w);
    ((ushort4*)out)[i] = o;
  }
}

// fused 4-weight conversion (blockIdx.y picks the matrix); n4 = 102400 each
__global__ __launch_bounds__(256) void cvt4_bf16(
    const float* __restrict__ i0, const float* __restrict__ i1,
    const float* __restrict__ i2, const float* __restrict__ i3,
    ushort* __restrict__ o0, ushort* __restrict__ o1,
    ushort* __restrict__ o2, ushort* __restrict__ o3, int n4) {
  const float* in = (blockIdx.y == 0) ? i0 : (blockIdx.y == 1) ? i1
                    : (blockIdx.y == 2) ? i2 : i3;
  ushort* out = (blockIdx.y == 0) ? o0 : (blockIdx.y == 1) ? o1
                : (blockIdx.y == 2) ? o2 : o3;
  int i = blockIdx.x * 256 + threadIdx.x;
  if (i < n4) {
    const float4 v = ((const float4*)in)[i];
    ushort4 o;
    o.x = f2bf(v.x); o.y = f2bf(v.y); o.z = f2bf(v.z); o.w = f2bf(v.w);
    ((ushort4*)out)[i] = o;
  }
}

// C = A(bf16 [M,640]) * W^T(bf16 [N,640]); 128x128 tile, BK=64, 4 waves.
// (r6's proven version — the r9 3-matrix fusion regressed non-attn 130->148us)
// MODE 0: QKV fused (blockIdx.y: 0-4 Q, 5-9 K, 10-14 V). Q/K -> [B,H,S,64]
//         (Q pre-scaled by QSCALE), V -> [B,H,64,S].
// MODE 1: out-proj + bias + residual -> fp32 [B,S,C].
template<int MODE>
__global__ __launch_bounds__(256) void gemm_k(
    const ushort* __restrict__ A, const ushort* __restrict__ W0,
    const ushort* __restrict__ W1, const ushort* __restrict__ W2,
    ushort* __restrict__ Qh, ushort* __restrict__ Kh, ushort* __restrict__ Vt,
    const float* __restrict__ bias, const float* __restrict__ residual,
    float* __restrict__ outf)
{
  __shared__ ushort As[128 * 64];
  __shared__ ushort Bs[128 * 64];
  const int t = threadIdx.x;
  const int lane = t & 63;
  const int w = t >> 6;
  const int quad = lane >> 4;
  const int l15 = lane & 15;
  const int m0 = blockIdx.x * 128;
  const int wub = t & ~63;

  int n0, mat;
  const ushort* W;
  if (MODE == 0) {
    mat = blockIdx.y / 5;
    n0 = (blockIdx.y % 5) * 128;
    W = (mat == 0) ? W0 : ((mat == 1) ? W1 : W2);
  } else {
    mat = 0;
    n0 = blockIdx.y * 128;
    W = W0;
  }
  const int qm = (w >> 1) * 64;
  const int qn = (w & 1) * 64;

  f32x4 acc[4][4];
  const f32x4 zero4 = {0.f, 0.f, 0.f, 0.f};
#pragma unroll
  for (int i = 0; i < 4; ++i)
#pragma unroll
    for (int j = 0; j < 4; ++j) acc[i][j] = zero4;

  for (int k0 = 0; k0 < Csz; k0 += 64) {
    __syncthreads();
#pragma unroll
    for (int s = 0; s < 4; ++s) {
      int L = s * 256 + t;
      int row = L >> 3, pc = L & 7;
      int c = pc ^ (row & 7);
      async16(A + (size_t)(m0 + row) * Csz + k0 + c * 8,
              (char*)As + (s * 256 + wub) * 16);
    }
#pragma unroll
    for (int s = 0; s < 4; ++s) {
      int L = s * 256 + t;
      int row = L >> 3, pc = L & 7;
      int c = pc ^ (row & 7);
      async16(W + (size_t)(n0 + row) * Csz + k0 + c * 8,
              (char*)Bs + (s * 256 + wub) * 16);
    }
    __syncthreads();
#pragma unroll
    for (int ks = 0; ks < 2; ++ks) {
      bf16x8 af[4], bfr[4];
#pragma unroll
      for (int i = 0; i < 4; ++i) {
        int row = qm + i * 16 + l15;
        int pc = (ks * 4 + quad) ^ (row & 7);
        af[i] = *(const bf16x8*)(As + row * 64 + pc * 8);
      }
#pragma unroll
      for (int j = 0; j < 4; ++j) {
        int row = qn + j * 16 + l15;
        int pc = (ks * 4 + quad) ^ (row & 7);
        bfr[j] = *(const bf16x8*)(Bs + row * 64 + pc * 8);
      }
#pragma unroll
      for (int i = 0; i < 4; ++i)
#pragma unroll
        for (int j = 0; j < 4; ++j)
          acc[i][j] = __builtin_amdgcn_mfma_f32_16x16x32_bf16(af[i], bfr[j], acc[i][j], 0, 0, 0);
    }
  }

  if (MODE == 0) {
    if (mat < 2) {
      ushort* __restrict__ dst = (mat == 0) ? Qh : Kh;
      const float sc = (mat == 0) ? QSCALE : 1.0f;
#pragma unroll
      for (int j = 0; j < 4; ++j) {
        int n = n0 + qn + j * 16 + l15;
        int h = n >> 6, dh = n & 63;
#pragma unroll
        for (int i = 0; i < 4; ++i) {
#pragma unroll
          for (int r = 0; r < 4; ++r) {
            int m = m0 + qm + i * 16 + quad * 4 + r;
            int b = m >> 12, sidx = m & 4095;
            dst[(((size_t)b * Hn + h) * Ssz + sidx) * Dh + dh] = f2bf(acc[i][j][r] * sc);
          }
        }
      }
    } else {
#pragma unroll
      for (int j = 0; j < 4; ++j) {
        int n = n0 + qn + j * 16 + l15;
        int h = n >> 6, dh = n & 63;
#pragma unroll
        for (int i = 0; i < 4; ++i) {
          int mb = m0 + qm + i * 16 + quad * 4;
          int b = mb >> 12, sidx = mb & 4095;
          ushort4 pk4;
          pk4.x = f2bf(acc[i][j][0]); pk4.y = f2bf(acc[i][j][1]);
          pk4.z = f2bf(acc[i][j][2]); pk4.w = f2bf(acc[i][j][3]);
          *(ushort4*)(Vt + (((size_t)b * Hn + h) * Dh + dh) * Ssz + sidx) = pk4;
        }
      }
    }
  } else {
#pragma unroll
    for (int j = 0; j < 4; ++j) {
      int n = n0 + qn + j * 16 + l15;
      float bs = bias[n];
#pragma unroll
      for (int i = 0; i < 4; ++i) {
#pragma unroll
        for (int r = 0; r < 4; ++r) {
          int m = m0 + qm + i * 16 + quad * 4 + r;
          size_t idx = (size_t)m * Csz + n;
          outf[idx] = acc[i][j][r] + bs + residual[idx];
        }
      }
    }
  }
}

// Flash attention v10 (fixed launch-args compile error; kernel unchanged):
// NO LDS, NO barriers, register-double-buffered K/V.
// 4 waves per block; each wave owns the SAME 64 q-columns but a DIFFERENT
// kv-quarter (split = wave id -> no duplicated loads within a block, and
// Opart combine handles the reduction). Waves free-run: phases drift so
// MFMA/VALU/VMEM overlap across the 8 resident waves/CU instead of the
// barrier convoy (r6/r9: pipes summed serially, 119us vs ~35us overlap floor).
// Per 32-kv iter: prefetch next K/V frags into the idle register buffer
// (8 global_load_dwordx4, ~600cyc latency hidden behind ~1500cyc compute),
// then QK (32x32x16, S^T=K*Q^T) -> exp2 -> xor-32 exchange -> PV (O^T=V^T*P^T).
// amdgpu_waves_per_eu(2) min-only: 256-VGPR budget for ~205-reg liveness ->
// no spill (r5/r7 failure mode), 2 waves/SIMD.
// Outputs UNNORMALIZED O^T partials + l partials; combine_k finishes.
__global__ __launch_bounds__(256)
__attribute__((amdgpu_waves_per_eu(2)))
void attn_k(
    const ushort* __restrict__ Qh, const ushort* __restrict__ Kh,
    const ushort* __restrict__ Vt, ushort* __restrict__ Opart,
    float* __restrict__ lpart)
{
  const int t = threadIdx.x;
  const int lane = t & 63;
  const int w = t >> 6;          // 0..3 = kv-split index
  const int l31 = lane & 31;
  const int hi = lane >> 5;
  const int bh = blockIdx.y;     // 0..19
  const ushort* __restrict__ Kb = Kh + (size_t)bh * Ssz * Dh;
  const ushort* __restrict__ Vb = Vt + (size_t)bh * Dh * Ssz;
  const int qbase = blockIdx.x * 64;
  const int kvbase = w * (Ssz / NSPLIT);   // wave-level kv split

  // preload Q B-frags for both q-halves: B[k=d][n=q], frag ks covers
  // d = ks*16 + hi*8 + j
  bf16x8 qf[2][4];
#pragma unroll
  for (int qh = 0; qh < 2; ++qh) {
    int q = qbase + qh * 32 + l31;
#pragma unroll
    for (int ks = 0; ks < 4; ++ks)
      qf[qh][ks] = *(const bf16x8*)(Qh + (size_t)bh * Ssz * Dh +
                                    (size_t)q * Dh + ks * 16 + hi * 8);
  }

  f32x16 z16;
#pragma unroll
  for (int i = 0; i < 16; ++i) z16[i] = 0.f;

  f32x16 Oa[2][2];   // [qh][mt]
#pragma unroll
  for (int qh = 0; qh < 2; ++qh)
#pragma unroll
    for (int mt = 0; mt < 2; ++mt) Oa[qh][mt] = z16;
  float lp[2] = {0.f, 0.f};

  // K frags: A[m=kv32][k=d]; lane: kv = kvoff+l31, d = ks*16+hi*8..+7
  // V frags: A[m=d][k=kv32]; lane: d = mt*32+l31, kv = kvoff+ks2l*16+hi*8..+7
#define LOADKV(KD, VD, kvoff)                                                  \
  {                                                                            \
    _Pragma("unroll") for (int ks = 0; ks < 4; ++ks)                           \
      KD[ks] = *(const bf16x8*)(Kb + (size_t)((kvoff) + l31) * Dh +            \
                                ks * 16 + hi * 8);                             \
    _Pragma("unroll") for (int ks2l = 0; ks2l < 2; ++ks2l)                     \
      _Pragma("unroll") for (int mt = 0; mt < 2; ++mt)                         \
        VD[ks2l][mt] = *(const bf16x8*)(Vb + (size_t)(mt * 32 + l31) * Ssz +   \
                                        (kvoff) + ks2l * 16 + hi * 8);         \
  }

  // one 32-kv tile: QK -> exp2 -> P^T exchange -> PV (proven r8 body)
#define BODY(CK, CV)                                                           \
  {                                                                            \
    _Pragma("unroll") for (int qh = 0; qh < 2; ++qh) {                         \
      f32x16 Sq;                                                               \
      _Pragma("unroll") for (int ks = 0; ks < 4; ++ks)                         \
        Sq = __builtin_amdgcn_mfma_f32_32x32x16_bf16(                          \
            CK[ks], qf[qh][ks], ks == 0 ? z16 : Sq, 0, 0, 0);                  \
      uint32_t pk[8];                                                          \
      _Pragma("unroll") for (int a = 0; a < 8; ++a) {                          \
        float p0 = fast_exp2(Sq[2 * a]);                                       \
        float p1 = fast_exp2(Sq[2 * a + 1]);                                   \
        lp[qh] += p0 + p1;                                                     \
        pk[a] = pack_bf16(p0, p1);                                             \
      }                                                                        \
      _Pragma("unroll") for (int ks2l = 0; ks2l < 2; ++ks2l) {                 \
        uint32_t xA0 = pk[4 * ks2l + 0], xA1 = pk[4 * ks2l + 1];               \
        uint32_t xB0 = pk[4 * ks2l + 2], xB1 = pk[4 * ks2l + 3];               \
        uint32_t own0 = hi ? xB0 : xA0, own1 = hi ? xB1 : xA1;                 \
        uint32_t snd0 = hi ? xA0 : xB0, snd1 = hi ? xA1 : xB1;                 \
        uint32_t rcv0 = (uint32_t)__shfl_xor((int)snd0, 32, 64);               \
        uint32_t rcv1 = (uint32_t)__shfl_xor((int)snd1, 32, 64);               \
        union { uint32_t u[4]; bf16x8 v; } pu;                                 \
        pu.u[0] = hi ? rcv0 : own0;                                            \
        pu.u[1] = hi ? rcv1 : own1;                                            \
        pu.u[2] = hi ? own0 : rcv0;                                            \
        pu.u[3] = hi ? own1 : rcv1;                                            \
        _Pragma("unroll") for (int mt = 0; mt < 2; ++mt)                       \
          Oa[qh][mt] = __builtin_amdgcn_mfma_f32_32x32x16_bf16(                \
              CV[ks2l][mt], pu.v, Oa[qh][mt], 0, 0, 0);                        \
      }                                                                        \
    }                                                                          \
  }

  bf16x8 K0[4], K1[4];
  bf16x8 V0[2][2], V1[2][2];

  LOADKV(K0, V0, kvbase);

  const int NIT2 = (Ssz / NSPLIT) / 64;  // 16 double-iterations
  for (int it2 = 0; it2 < NIT2; ++it2) {
    const int kv0 = kvbase + it2 * 64;
    // prefetch tile B while computing tile A
    LOADKV(K1, V1, kv0 + 32);
    BODY(K0, V0);
    // prefetch next tile A while computing tile B
    if (it2 + 1 < NIT2) {
      LOADKV(K0, V0, kv0 + 64);
    }
    BODY(K1, V1);
  }
#undef LOADKV
#undef BODY

  // epilogue: write UNNORMALIZED partials (split = wave id w).
  const size_t prow_base = (size_t)w * QROWS + (size_t)bh * Ssz;
#pragma unroll
  for (int qh = 0; qh < 2; ++qh) {
    float l_part = lp[qh];
    float l_tot = l_part + __shfl_xor(l_part, 32, 64);
    int q = qbase + qh * 32 + l31;
    if (hi == 0) lpart[prow_base + q] = l_tot;
    ushort* dst = Opart + (prow_base + q) * 64;
#pragma unroll
    for (int mt = 0; mt < 2; ++mt) {
#pragma unroll
      for (int g = 0; g < 4; ++g) {
        int dh0 = mt * 32 + 8 * g + 4 * hi;
        uint2 val;
        val.x = pack_bf16(Oa[qh][mt][4 * g + 0], Oa[qh][mt][4 * g + 1]);
        val.y = pack_bf16(Oa[qh][mt][4 * g + 2], Oa[qh][mt][4 * g + 3]);
        *(uint2*)(dst + dh0) = val;
      }
    }
  }
}

// sum NSPLIT partials, normalize by total l, scatter to attnb [B,S,C] bf16
__global__ __launch_bounds__(256) void combine_k(
    const ushort* __restrict__ Opart, const float* __restrict__ lpart,
    ushort* __restrict__ attnb)
{
  int gid = blockIdx.x * 256 + threadIdx.x;   // QROWS*16 total
  int row = gid >> 4;                         // 0..QROWS-1
  int dh0 = (gid & 15) * 4;
  int bh = row >> 12, q = row & 4095;
  int b = bh / Hn, h = bh % Hn;
  float a0 = 0.f, a1 = 0.f, a2 = 0.f, a3 = 0.f, lsum = 0.f;
#pragma unroll
  for (int sp = 0; sp < NSPLIT; ++sp) {
    uint2 v = *(const uint2*)(Opart + ((size_t)sp * QROWS + row) * 64 + dh0);
    a0 += bf_lo(v.x); a1 += bf_hi(v.x);
    a2 += bf_lo(v.y); a3 += bf_hi(v.y);
    lsum += lpart[(size_t)sp * QROWS + row];
  }
  float inv = 1.0f / lsum;
  uint2 o;
  o.x = pack_bf16(a0 * inv, a1 * inv);
  o.y = pack_bf16(a2 * inv, a3 * inv);
  *(uint2*)(attnb + ((size_t)b * Ssz + q) * Csz + h * Dh + dh0) = o;
}

extern "C" void kernel_launch(void* const* d_in, const int* in_sizes, int n_in,
                              void* d_out, int out_size, void* d_ws, size_t ws_size,
                              hipStream_t stream) {
  (void)in_sizes; (void)n_in; (void)out_size; (void)ws_size;
  const float* hs = (const float*)d_in[0];
  const float* Wq = (const float*)d_in[1];
  const float* Wk = (const float*)d_in[2];
  const float* Wv = (const float*)d_in[3];
  const float* Wo = (const float*)d_in[4];
  const float* bo = (const float*)d_in[5];
  float* out = (float*)d_out;

  char* ws = (char*)d_ws;
  ushort* Xbf = (ushort*)(ws);                               // 10485760 B
  ushort* Wqb = (ushort*)(ws + 10485760);                    // 819200 B each
  ushort* Wkb = (ushort*)(ws + 10485760 + 819200);
  ushort* Wvb = (ushort*)(ws + 10485760 + 2 * 819200);
  ushort* Wob = (ushort*)(ws + 10485760 + 3 * 819200);
  ushort* Qh  = (ushort*)(ws + 13762560);                    // [20,4096,64]
  ushort* Kh  = (ushort*)(ws + 13762560 + 10485760);
  ushort* Vt  = (ushort*)(ws + 13762560 + 2 * 10485760);     // [20,64,4096]
  ushort* attnb = (ushort*)(ws + 13762560 + 3 * 10485760);   // [8192,640]
  ushort* Opart = (ushort*)(ws + 55705600);                  // [4][81920][64] bf16 = 41.9MB
  float*  lpart = (float*)(ws + 55705600 + 41943040);        // [4][81920] f32

  hipLaunchKernelGGL(cvt_bf16, dim3(5120), dim3(256), 0, stream, hs, Xbf, 1310720);
  hipLaunchKernelGGL(cvt4_bf16, dim3(400, 4), dim3(256), 0, stream,
                     Wq, Wk, Wv, Wo, Wqb, Wkb, Wvb, Wob, 102400);

  hipLaunchKernelGGL((gemm_k<0>), dim3(64, 15), dim3(256), 0, stream,
                     Xbf, Wqb, Wkb, Wvb, Qh, Kh, Vt, (const float*)nullptr,
                     (const float*)nullptr, (float*)nullptr);
  hipLaunchKernelGGL(attn_k, dim3(64, 20), dim3(256), 0, stream,
                     Qh, Kh, Vt, Opart, lpart);
  hipLaunchKernelGGL(combine_k, dim3(QROWS / 16), dim3(256), 0, stream,
                     Opart, lpart, attnb);
  hipLaunchKernelGGL((gemm_k<1>), dim3(64, 5), dim3(256), 0, stream,
                     attnb, Wob, (const ushort*)nullptr, (const ushort*)nullptr,
                     (ushort*)nullptr, (ushort*)nullptr, (ushort*)nullptr,
                     bo, hs, out);
}